// Round 23
// baseline (273.657 us; speedup 1.0000x reference)
//
#include <hip/hip_runtime.h>
#include <hip/hip_bf16.h>

#define A_NUM 15
#define HDIM 128
#define WDIM 128
#define HW (HDIM*WDIM)
#define PER_IMG (A_NUM*HW)      // 245760
#define NIMG 2
#define PRE_N 6000
#define POST_N 1000
#define NBLK 94                 // ceil(6000/64)
#define NPAD (NBLK*64)          // 6016
#define SORTN 8192
#define CHUNK4 4096
#define NBIN 16384
#define HPART 16                // hist blocks per image
#define PROD_T 448              // producer threads (waves 1..7)
#define WPT 14                  // words per producer thread (448*14 >= 6016)

typedef unsigned long long ull;

// ws layout (bytes)
#define META_OFF   0u           // [0..1]=selcnt [2..3]=T(ord16)
#define HIST_OFF   64u          // 2*16384*u32 = 131072
#define SEL_OFF    131136u      // 2*8192*u64 = 131072
#define BOX_OFF    262208u      // 6*2*6016*f32 = 288768
#define VALIDW_OFF 550976u      // 2*128*u64 = 2048
#define MASK_OFF   553024u      // 2*94*6016*u64 = 9048064 (end 9,601,088)

__device__ __forceinline__ unsigned int f2ord(float f) {
    unsigned int u = __float_as_uint(f);
    return (u & 0x80000000u) ? ~u : (u | 0x80000000u);
}
__device__ __forceinline__ float ord2f(unsigned int u) {
    unsigned int s = (u & 0x80000000u) ? (u ^ 0x80000000u) : ~u;
    return __uint_as_float(s);
}
__device__ __forceinline__ ull readlane64(ull v, int l) {
    unsigned int lo = (unsigned int)__builtin_amdgcn_readlane((int)(unsigned int)v, l);
    unsigned int hi = (unsigned int)__builtin_amdgcn_readlane((int)(unsigned int)(v >> 32), l);
    return ((ull)hi << 32) | lo;
}
// LDS-only barrier: drain lgkm but leave global loads in flight.
__device__ __forceinline__ void barrier_lds() {
    asm volatile("s_waitcnt lgkmcnt(0)" ::: "memory");
    __builtin_amdgcn_s_barrier();
    asm volatile("" ::: "memory");
}

// ---------- 16384-bin histogram of ordered bits [30:16], LDS + global merge
__global__ __launch_bounds__(1024) void k_hist16(const float* __restrict__ cls,
                                                 unsigned int* __restrict__ hist) {
    __shared__ unsigned int h[NBIN];
    int img = blockIdx.y, part = blockIdx.x;
    int t = threadIdx.x;
    for (int b = t; b < NBIN; b += 1024) h[b] = 0;
    __syncthreads();
    int base = img * PER_IMG + part * (PER_IMG / HPART);
    for (int e = t; e < PER_IMG / HPART; e += 1024) {
        unsigned int u = f2ord(cls[base + e]);
        unsigned int bin = (u >> 16) - 0x8000u;
        if (bin > (NBIN - 1)) bin = NBIN - 1;  // safety clamp (impossible for [0,1))
        atomicAdd(&h[bin], 1u);
    }
    __syncthreads();
    unsigned int* hp = hist + (size_t)img * NBIN;
    for (int b = t; b < NBIN; b += 1024)
        if (h[b]) atomicAdd(&hp[b], h[b]);
}

// ---------- parallel suffix-scan: find max bin T with suffix >= PRE_N ----
__global__ __launch_bounds__(1024) void k_scan16(const unsigned int* __restrict__ hist,
                                                 unsigned int* __restrict__ meta) {
    __shared__ unsigned int csum[1024];
    __shared__ unsigned int aux[64];
    __shared__ unsigned int binv[16];
    int img = blockIdx.x, t = threadIdx.x;
    const unsigned int* hp = hist + (size_t)img * NBIN;
    unsigned int s = 0;
    #pragma unroll
    for (int q = 0; q < 16; ++q) s += hp[t * 16 + q];
    csum[t] = s;
    __syncthreads();
    if (t < 64) {
        unsigned int x = 0;
        #pragma unroll
        for (int q = 0; q < 16; ++q) x += csum[t * 16 + q];
        aux[t] = x;
    }
    __syncthreads();
    if (t < 64) {
        unsigned int suf = 0;
        for (int q = t; q < 64; ++q) suf += aux[q];
        ull mb1 = __ballot(suf >= PRE_N);
        int sstar = 63 - __clzll(mb1);
        unsigned int sufnext = (unsigned)__shfl((int)suf, (sstar + 1) & 63);
        unsigned int cumAbove = (sstar == 63) ? 0u : sufnext;
        unsigned int sufC = 0;
        if (t < 16) {
            for (int q = sstar * 16 + t; q < sstar * 16 + 16; ++q) sufC += csum[q];
            sufC += cumAbove;
        }
        ull mb2 = __ballot((t < 16) && (sufC >= PRE_N));
        int crel = 63 - __clzll(mb2);
        int cstar = sstar * 16 + crel;
        unsigned int cumAbove2 = (crel == 15) ? cumAbove : (unsigned)__shfl((int)sufC, crel + 1);
        if (t < 16) binv[t] = hp[cstar * 16 + t];
        unsigned int sufB = 0;
        if (t < 16) {
            for (int q = t; q < 16; ++q) sufB += binv[q];
            sufB += cumAbove2;
        }
        ull mb3 = __ballot((t < 16) && (sufB >= PRE_N));
        int brel = 63 - __clzll(mb3);
        if (t == 0) {
            meta[2 + img] = (unsigned)(cstar * 16 + brel) + 0x8000u;
            meta[img] = 0u;  // reset select counters for gather (every replay)
        }
    }
}

// ---------- gather candidates with (ord>>16) >= T, block-aggregated ------
__global__ __launch_bounds__(1024) void k_gather(const float* __restrict__ cls,
                                                 unsigned int* __restrict__ meta,
                                                 ull* __restrict__ selkeys) {
    __shared__ unsigned int lcnt[NIMG], lbase[NIMG];
    int t = threadIdx.x;
    int tid = blockIdx.x * 1024 + t;
    if (t < NIMG) lcnt[t] = 0;
    __syncthreads();
    unsigned int T0 = meta[2], T1 = meta[3];
    int a = tid / HW;
    int pos = tid - a * HW;          // h*WDIM + w
    int m = pos * A_NUM + a;         // (h,w,a) flattened order
    int lane = t & 63;
    unsigned int uv[NIMG];
    bool pr[NIMG];
    unsigned int lofs[NIMG];
    #pragma unroll
    for (int img = 0; img < NIMG; ++img) {
        unsigned int T = img ? T1 : T0;
        unsigned int u = f2ord(cls[img * PER_IMG + tid]);
        uv[img] = u;
        bool pred = (u >> 16) >= T;
        pr[img] = pred;
        ull mball = __ballot((int)pred);
        unsigned int o = 0;
        if (pred) {
            int leader = __ffsll((long long)mball) - 1;
            unsigned int wbase = 0;
            if (lane == leader) wbase = atomicAdd(&lcnt[img], (unsigned)__popcll(mball));
            wbase = (unsigned)__shfl((int)wbase, leader);
            o = wbase + (unsigned)__popcll(mball & ((1ull << lane) - 1ull));
        }
        lofs[img] = o;
    }
    __syncthreads();
    if (t < NIMG) lbase[t] = atomicAdd(&meta[t], lcnt[t]);
    __syncthreads();
    #pragma unroll
    for (int img = 0; img < NIMG; ++img) {
        if (pr[img]) {
            unsigned int p = lbase[img] + lofs[img];
            if (p < SORTN)
                selkeys[(size_t)img * SORTN + p] =
                    ((ull)(~uv[img]) << 32) | (unsigned int)m;
        }
    }
}

// ---------- bitonic: local sort of 4096-chunks (asc/desc), 1024 thr ------
__global__ __launch_bounds__(1024) void k_sortA(ull* __restrict__ selkeys,
                                                const unsigned int* __restrict__ meta) {
    __shared__ ull key[CHUNK4];   // 32 KB
    int img = blockIdx.x >> 1, c = blockIdx.x & 1;
    unsigned int cnt = meta[img];
    if (cnt > SORTN) cnt = SORTN;
    ull* g = selkeys + (size_t)img * SORTN;
    int base = c * CHUNK4;
    for (int i = threadIdx.x; i < CHUNK4; i += 1024)
        key[i] = (base + i < (int)cnt) ? g[base + i] : ~0ull;
    __syncthreads();
    bool desc = (c & 1);
    for (int k = 2; k <= CHUNK4; k <<= 1) {
        for (int j = k >> 1; j > 0; j >>= 1) {
            for (int p = threadIdx.x; p < CHUNK4 / 2; p += 1024) {
                int i = ((p & ~(j - 1)) << 1) | (p & (j - 1));
                int x = i | j;
                bool up = (((i & k) == 0) != desc);
                ull A = key[i], B = key[x];
                if ((A > B) == up) { key[i] = B; key[x] = A; }
            }
            __syncthreads();
        }
    }
    for (int i = threadIdx.x; i < CHUNK4; i += 1024) g[base + i] = key[i];
}

// ---------- final k=8192 bitonic merge + INLINE decode (keys in LDS) -----
__global__ __launch_bounds__(1024) void k_sortdec(const ull* __restrict__ selkeys,
                                                  const float* __restrict__ bbox,
                                                  const float* __restrict__ anchors,
                                                  const float* __restrict__ iminfo,
                                                  float* __restrict__ boxsoa,
                                                  ull* __restrict__ validwArr) {
    __shared__ ull key[SORTN];    // 64 KB
    int img = blockIdx.x;
    int t = threadIdx.x;
    const ull* g = selkeys + (size_t)img * SORTN;
    for (int i = t; i < SORTN; i += 1024) key[i] = g[i];
    __syncthreads();
    for (int j = SORTN / 2; j > 0; j >>= 1) {
        for (int p = t; p < SORTN / 2; p += 1024) {
            int i = ((p & ~(j - 1)) << 1) | (p & (j - 1));
            int x = i | j;
            ull A = key[i], B = key[x];   // k=8192 -> ascending everywhere
            if (A > B) { key[i] = B; key[x] = A; }
        }
        __syncthreads();
    }
    // decode top-6000 straight from LDS (boxes + per-block valid ballots)
    float him = iminfo[img * 3 + 0], wim = iminfo[img * 3 + 1], scale = iminfo[img * 3 + 2];
    float wmax = __fsub_rn(wim, 1.0f), hmax = __fsub_rn(him, 1.0f);
    const float* bb = bbox + (size_t)img * 4 * A_NUM * HW;
    for (int rbase = 0; rbase < PRE_N; rbase += 1024) {
        int r = rbase + t;
        bool in = r < PRE_N;
        ull keyv = key[in ? r : 0];
        unsigned int m = (unsigned int)(keyv & 0xFFFFFFFFu);
        unsigned int u = ~(unsigned int)(keyv >> 32);
        float score = ord2f(u);
        int q = m / A_NUM;
        int a = m - q * A_NUM;
        int w = q & (WDIM - 1);
        int h = q >> 7;
        // reference's meshgrid quirk -> x-shift from h, y-shift from w
        float sx = (float)h * 8.0f;
        float sy = (float)w * 8.0f;
        float a0 = __fadd_rn(anchors[a * 4 + 0], sx);
        float a1 = __fadd_rn(anchors[a * 4 + 1], sy);
        float a2 = __fadd_rn(anchors[a * 4 + 2], sx);
        float a3 = __fadd_rn(anchors[a * 4 + 3], sy);
        float ws = __fadd_rn(__fsub_rn(a2, a0), 1.0f);
        float hs = __fadd_rn(__fsub_rn(a3, a1), 1.0f);
        float cx = __fadd_rn(a0, __fmul_rn(0.5f, ws));
        float cy = __fadd_rn(a1, __fmul_rn(0.5f, hs));
        int base = h * WDIM + w;
        float dx = bb[(a * 4 + 0) * HW + base];
        float dy = bb[(a * 4 + 1) * HW + base];
        float dwv = bb[(a * 4 + 2) * HW + base];
        float dhv = bb[(a * 4 + 3) * HW + base];
        const float CLIPV = 4.135166556742356f;  // np.float32(log(1000/16))
        float dw = fminf(dwv, CLIPV);
        float dh = fminf(dhv, CLIPV);
        float pcx = __fadd_rn(__fmul_rn(dx, ws), cx);
        float pcy = __fadd_rn(__fmul_rn(dy, hs), cy);
        float pw = __fmul_rn(expf(dw), ws);
        float ph = __fmul_rn(expf(dh), hs);
        float x1 = __fsub_rn(pcx, __fmul_rn(0.5f, pw));
        float y1 = __fsub_rn(pcy, __fmul_rn(0.5f, ph));
        float x2 = __fsub_rn(__fadd_rn(pcx, __fmul_rn(0.5f, pw)), 1.0f);
        float y2 = __fsub_rn(__fadd_rn(pcy, __fmul_rn(0.5f, ph)), 1.0f);
        x1 = fminf(fmaxf(x1, 0.0f), wmax);
        y1 = fminf(fmaxf(y1, 0.0f), hmax);
        x2 = fminf(fmaxf(x2, 0.0f), wmax);
        y2 = fminf(fmaxf(y2, 0.0f), hmax);
        float bws = __fadd_rn(__fsub_rn(x2, x1), 1.0f);
        float bhs = __fadd_rn(__fsub_rn(y2, y1), 1.0f);
        float minsz = __fmul_rn(0.0f, scale);  // MIN_SIZE * scale
        bool valid = (bws >= minsz) && (bhs >= minsz) &&
                     (__fadd_rn(x1, __fdiv_rn(bws, 2.0f)) < wim) &&
                     (__fadd_rn(y1, __fdiv_rn(bhs, 2.0f)) < him);
        float area = __fmul_rn(bws, bhs);
        if (in) {
            boxsoa[(0 * NIMG + img) * NPAD + r] = x1;
            boxsoa[(1 * NIMG + img) * NPAD + r] = y1;
            boxsoa[(2 * NIMG + img) * NPAD + r] = x2;
            boxsoa[(3 * NIMG + img) * NPAD + r] = y2;
            boxsoa[(4 * NIMG + img) * NPAD + r] = area;
            boxsoa[(5 * NIMG + img) * NPAD + r] = score;
        }
        ull bw = __ballot((int)(in && valid));
        if ((t & 63) == 0) {
            int blk = r >> 6;
            if (blk < NBLK) validwArr[img * 128 + blk] = bw;
        }
    }
}

// ---------- COLUMN-major suppression matrix Mc[img][cb][r] ---------------
// Mc[cb][r] bit jj = iou(box r, box cb*64+jj) > 0.7, (cb*64+jj) != r.
// Only row-blocks rb <= cb computed (reduce reads rows r <= cb*64+63).
__global__ __launch_bounds__(256) void k_mask(const float* __restrict__ boxsoa,
                                              ull* __restrict__ Mc) {
    int cb = blockIdx.x, rbq = blockIdx.y, img = blockIdx.z;
    if ((rbq << 2) > cb) return;          // whole quad below row<=col boundary
    int t = threadIdx.x, wv = t >> 6, lane = t & 63;
    __shared__ float jx1[64], jy1[64], jx2[64], jy2[64], jar[64];
    const float* X1 = boxsoa + (0 * NIMG + img) * NPAD;
    const float* Y1 = boxsoa + (1 * NIMG + img) * NPAD;
    const float* X2 = boxsoa + (2 * NIMG + img) * NPAD;
    const float* Y2 = boxsoa + (3 * NIMG + img) * NPAD;
    const float* AR = boxsoa + (4 * NIMG + img) * NPAD;
    int j0 = cb * 64;
    if (t < 64) {
        int jidx = j0 + t;
        bool jin = jidx < PRE_N;
        jx1[t] = jin ? X1[jidx] : 0.0f;
        jy1[t] = jin ? Y1[jidx] : 0.0f;
        jx2[t] = jin ? X2[jidx] : 0.0f;
        jy2[t] = jin ? Y2[jidx] : 0.0f;
        jar[t] = jin ? AR[jidx] : 1.0f;
    }
    __syncthreads();
    int rb = rbq * 4 + wv;
    if (rb > cb) return;
    int r = rb * 64 + lane;
    ull bits = 0ULL;
    if (r < PRE_N) {
        float x1 = X1[r], y1 = Y1[r], x2 = X2[r], y2 = Y2[r], ai = AR[r];
        for (int jj = 0; jj < 64; ++jj) {
            int j = j0 + jj;
            if (j == r || j >= PRE_N) continue;
            float ix1 = fmaxf(x1, jx1[jj]);
            float iy1 = fmaxf(y1, jy1[jj]);
            float ix2 = fminf(x2, jx2[jj]);
            float iy2 = fminf(y2, jy2[jj]);
            float iw = fmaxf(__fadd_rn(__fsub_rn(ix2, ix1), 1.0f), 0.0f);
            float ih = fmaxf(__fadd_rn(__fsub_rn(iy2, iy1), 1.0f), 0.0f);
            float inter = __fmul_rn(iw, ih);
            float denom = __fsub_rn(__fadd_rn(ai, jar[jj]), inter);
            float iou = __fdiv_rn(inter, denom);
            if (iou > 0.7f) bits |= (1ULL << jj);
        }
    }
    Mc[((size_t)img * NBLK + cb) * NPAD + r] = bits;
}

// ---------- greedy reduce: R20 structure + latency-batched fold ----------
// Step ib:
//   wave0:   sup = OR(partial[ib&1][1..7]) | fix(block ib-1 @ col ib,
//            masked by keptLDS[ib-1]) -> butterfly -> readlane chain.
//   waves1-7: ds_write col ib+2 (2-step parity regs); load col ib+4;
//            fold col ib+1 over blocks 0..ib-1 into partial[(ib+1)&1].
// FOLD IS BATCHED 4 STRIDES AT A TIME: 8 independent LDS reads issued
// per batch -> one lgkm latency window per 4 strides (the rolled loop's
// serialized per-iteration LDS latency was the hidden per-step ceiling).
__global__ __launch_bounds__(512, 1) void k_reduce(const ull* __restrict__ Mc,
                                                   const ull* __restrict__ validwArr,
                                                   const float* __restrict__ boxsoa,
                                                   float* __restrict__ out) {
    __shared__ ull buf[3][NPAD];          // 144384 B ring of 3 columns
    __shared__ ull keptLDS[NBLK];
    __shared__ ull partial[2][8][64];     // [parity][wave][lane]
    __shared__ unsigned short s_list[POST_N];
    __shared__ int s_stop, s_cnt;
    int img = blockIdx.x;
    int tid = threadIdx.x;
    int wv = tid >> 6, lane = tid & 63;
    const ull* MCI = Mc + (size_t)img * NBLK * NPAD;
    ull vw_a = 0, vw_b = 0;
    ull rbufA[WPT], rbufB[WPT];           // parity 0 / parity 1 reg buffers
    #pragma unroll
    for (int q = 0; q < WPT; ++q) { rbufA[q] = 0ULL; rbufB[q] = 0ULL; }
    int pid = tid - 64;
    if (wv == 0) {
        vw_a = validwArr[img * 128 + lane];
        vw_b = (lane + 64 < NBLK) ? validwArr[img * 128 + lane + 64] : 0ULL;
        if (lane == 0) { s_stop = 0; s_cnt = 0; }
        partial[0][0][lane] = 0ULL;       // wave0 never writes partials later
        partial[1][0][lane] = 0ULL;
    } else {
        // prologue: col0 -> buf[0]; col1 -> buf[1]; col2 -> rbufA; col3 -> rbufB
        #pragma unroll
        for (int q = 0; q < WPT; ++q) {
            int w = pid + PROD_T * q;
            rbufA[q] = (w < 64) ? MCI[w] : 0ULL;
        }
        #pragma unroll
        for (int q = 0; q < WPT; ++q) {
            int w = pid + PROD_T * q;
            if (w < 64) buf[0][w] = rbufA[q];
        }
        #pragma unroll
        for (int q = 0; q < WPT; ++q) {
            int w = pid + PROD_T * q;
            rbufB[q] = (w < 128) ? MCI[NPAD + w] : 0ULL;
        }
        #pragma unroll
        for (int q = 0; q < WPT; ++q) {
            int w = pid + PROD_T * q;
            if (w < 128) buf[1][w] = rbufB[q];
        }
        #pragma unroll
        for (int q = 0; q < WPT; ++q) {
            int w = pid + PROD_T * q;
            rbufA[q] = (w < 192) ? MCI[2 * (size_t)NPAD + w] : 0ULL;
        }
        #pragma unroll
        for (int q = 0; q < WPT; ++q) {
            int w = pid + PROD_T * q;
            rbufB[q] = (w < 256) ? MCI[3 * (size_t)NPAD + w] : 0ULL;
        }
        // zero partials for both parities (wave q covers its own slot)
        partial[0][wv][lane] = 0ULL;
        partial[1][wv][lane] = 0ULL;
    }
    __syncthreads();
    int cnt = 0;
    for (int ib = 0; ib < NBLK; ++ib) {
        int bcur = ib % 3, bn1 = (ib + 1) % 3, bn2 = (ib + 2) % 3;
        if (wv == 0) {
            // ---- sup = partials(col ib: blocks 0..ib-2) | fix(block ib-1)
            ull acc = 0ULL;
            if (ib > 0) {
                #pragma unroll
                for (int q = 1; q < 8; ++q) acc |= partial[ib & 1][q][lane];
                ull kwp = keptLDS[ib - 1];
                acc |= (0ULL - ((kwp >> lane) & 1ULL)) & buf[bcur][(ib - 1) * 64 + lane];
            }
            unsigned int lo = (unsigned)acc, hi = (unsigned)(acc >> 32);
            #pragma unroll
            for (int s2 = 1; s2 < 64; s2 <<= 1) {
                lo |= (unsigned)__shfl_xor((int)lo, s2);
                hi |= (unsigned)__shfl_xor((int)hi, s2);
            }
            ull sup = ((ull)hi << 32) | lo;
            ull validw = (ib < 64) ? readlane64(vw_a, ib) : readlane64(vw_b, ib - 64);
            ull d = buf[bcur][ib * 64 + lane];
            ull live = validw & ~sup;
            unsigned int dlo = (unsigned)d, dhi = (unsigned)(d >> 32);
            ull keptb = 0ULL;
            while (live) {
                int b = __ffsll((long long)live) - 1;
                keptb |= 1ULL << b;
                if (lane == 0) s_list[cnt] = (unsigned short)(ib * 64 + b);
                ++cnt;
                if (cnt >= POST_N) break;
                unsigned int rl = (unsigned)__builtin_amdgcn_readlane((int)dlo, b);
                unsigned int rh = (unsigned)__builtin_amdgcn_readlane((int)dhi, b);
                live &= ~(((ull)rh << 32) | rl);
                live &= ~(1ULL << b);
            }
            if (lane == 0) {
                keptLDS[ib] = keptb;
                s_cnt = cnt;
                if (cnt >= POST_N) s_stop = 1;
            }
        } else {
            // ---- stage: ds_write col ib+2 (loaded 2 steps ago); load col ib+4
            int c_w = ib + 2;
            if (c_w < NBLK) {
                int Ww = (c_w + 1) * 64;
                if (Ww > NPAD) Ww = NPAD;
                if (ib & 1) {
                    #pragma unroll
                    for (int q = 0; q < WPT; ++q) {
                        int w = pid + PROD_T * q;
                        if (w < Ww) buf[bn2][w] = rbufB[q];
                    }
                } else {
                    #pragma unroll
                    for (int q = 0; q < WPT; ++q) {
                        int w = pid + PROD_T * q;
                        if (w < Ww) buf[bn2][w] = rbufA[q];
                    }
                }
            }
            int c_l = ib + 4;
            if (c_l < NBLK) {
                int Wn = (c_l + 1) * 64;
                if (Wn > NPAD) Wn = NPAD;
                const ull* gn = MCI + (size_t)c_l * NPAD;
                if (ib & 1) {
                    #pragma unroll
                    for (int q = 0; q < WPT; ++q) {
                        int w = pid + PROD_T * q;
                        rbufB[q] = (w < Wn) ? gn[w] : 0ULL;
                    }
                } else {
                    #pragma unroll
                    for (int q = 0; q < WPT; ++q) {
                        int w = pid + PROD_T * q;
                        rbufA[q] = (w < Wn) ? gn[w] : 0ULL;
                    }
                }
            }
            // ---- fold col ib+1 over blocks 0..ib-1 (batched 4 strides) ----
            if (ib + 1 < NBLK) {
                ull part = 0ULL;
                int u = wv - 1;                 // 0..6
                int ulim = ib - 1;
                for (; u + 21 <= ulim; u += 28) {
                    ull k0 = keptLDS[u];
                    ull k1 = keptLDS[u + 7];
                    ull k2 = keptLDS[u + 14];
                    ull k3 = keptLDS[u + 21];
                    ull v0 = buf[bn1][(u) * 64 + lane];
                    ull v1 = buf[bn1][(u + 7) * 64 + lane];
                    ull v2 = buf[bn1][(u + 14) * 64 + lane];
                    ull v3 = buf[bn1][(u + 21) * 64 + lane];
                    part |= ((0ULL - ((k0 >> lane) & 1ULL)) & v0)
                          | ((0ULL - ((k1 >> lane) & 1ULL)) & v1)
                          | ((0ULL - ((k2 >> lane) & 1ULL)) & v2)
                          | ((0ULL - ((k3 >> lane) & 1ULL)) & v3);
                }
                for (; u <= ulim; u += 7) {
                    ull kw = keptLDS[u];
                    ull v = buf[bn1][u * 64 + lane];
                    part |= (0ULL - ((kw >> lane) & 1ULL)) & v;
                }
                partial[(ib + 1) & 1][wv][lane] = part;
            }
        }
        barrier_lds();                    // ONE barrier per step
        if (s_stop) break;
    }
    // drain outstanding producer loads before exit (determinism across replays)
    asm volatile("s_waitcnt vmcnt(0) lgkmcnt(0)" ::: "memory");
    __syncthreads();
    int total = s_cnt > POST_N ? POST_N : s_cnt;
    for (int k = tid; k < POST_N; k += 512) {
        float x1 = 0.0f, y1 = 0.0f, x2 = 0.0f, y2 = 0.0f, sc = -1.0f;
        if (k < total) {
            int r = (int)s_list[k];
            x1 = boxsoa[(0 * NIMG + img) * NPAD + r];
            y1 = boxsoa[(1 * NIMG + img) * NPAD + r];
            x2 = boxsoa[(2 * NIMG + img) * NPAD + r];
            y2 = boxsoa[(3 * NIMG + img) * NPAD + r];
            sc = boxsoa[(5 * NIMG + img) * NPAD + r];
        }
        float* roi = out + (size_t)(img * POST_N + k) * 5;
        roi[0] = (float)img;
        roi[1] = x1;
        roi[2] = y1;
        roi[3] = x2;
        roi[4] = y2;
        out[NIMG * POST_N * 5 + img * POST_N + k] = sc;
    }
}

extern "C" void kernel_launch(void* const* d_in, const int* in_sizes, int n_in,
                              void* d_out, int out_size, void* d_ws, size_t ws_size,
                              hipStream_t stream) {
    const float* cls = (const float*)d_in[0];
    const float* bbox = (const float*)d_in[1];
    const float* iminfo = (const float*)d_in[2];
    const float* anchors = (const float*)d_in[3];
    float* out = (float*)d_out;
    char* ws = (char*)d_ws;

    unsigned int* meta = (unsigned int*)(ws + META_OFF);
    unsigned int* hist = (unsigned int*)(ws + HIST_OFF);
    ull* selkeys = (ull*)(ws + SEL_OFF);
    float* boxsoa = (float*)(ws + BOX_OFF);
    ull* validwArr = (ull*)(ws + VALIDW_OFF);
    ull* mask = (ull*)(ws + MASK_OFF);

    hipMemsetAsync(hist, 0, (size_t)NIMG * NBIN * sizeof(unsigned int), stream);
    k_hist16<<<dim3(HPART, NIMG), 1024, 0, stream>>>(cls, hist);
    k_scan16<<<NIMG, 1024, 0, stream>>>(hist, meta);
    k_gather<<<PER_IMG / 1024, 1024, 0, stream>>>(cls, meta, selkeys);
    k_sortA<<<2 * NIMG, 1024, 0, stream>>>(selkeys, meta);
    k_sortdec<<<NIMG, 1024, 0, stream>>>(selkeys, bbox, anchors, iminfo, boxsoa, validwArr);
    k_mask<<<dim3(NBLK, (NBLK + 3) / 4, NIMG), 256, 0, stream>>>(boxsoa, mask);
    k_reduce<<<NIMG, 512, 0, stream>>>(mask, validwArr, boxsoa, out);
}

// Round 24
// 237.383 us; speedup vs baseline: 1.1528x; 1.1528x over previous
//
#include <hip/hip_runtime.h>
#include <hip/hip_bf16.h>

#define A_NUM 15
#define HDIM 128
#define WDIM 128
#define HW (HDIM*WDIM)
#define PER_IMG (A_NUM*HW)      // 245760
#define NIMG 2
#define PRE_N 6000
#define POST_N 1000
#define NBLK 94                 // ceil(6000/64)
#define NPAD (NBLK*64)          // 6016
#define SORTN 8192
#define CHUNK4 4096
#define NBIN 16384
#define HPART 16                // hist blocks per image
#define PROD_T 448              // producer threads (waves 1..7)
#define WPT 14                  // words per producer thread (448*14 >= 6016)

typedef unsigned long long ull;

// ws layout (bytes)
#define META_OFF   0u           // [0..1]=selcnt [2..3]=T(ord16)
#define HIST_OFF   64u          // 2*16384*u32 = 131072
#define SEL_OFF    131136u      // 2*8192*u64 = 131072
#define BOX_OFF    262208u      // 6*2*6016*f32 = 288768
#define VALIDW_OFF 550976u      // 2*128*u64 = 2048
#define MASK_OFF   553024u      // 2*94*6016*u64 = 9048064 (end 9,601,088)

__device__ __forceinline__ unsigned int f2ord(float f) {
    unsigned int u = __float_as_uint(f);
    return (u & 0x80000000u) ? ~u : (u | 0x80000000u);
}
__device__ __forceinline__ float ord2f(unsigned int u) {
    unsigned int s = (u & 0x80000000u) ? (u ^ 0x80000000u) : ~u;
    return __uint_as_float(s);
}
__device__ __forceinline__ ull readlane64(ull v, int l) {
    unsigned int lo = (unsigned int)__builtin_amdgcn_readlane((int)(unsigned int)v, l);
    unsigned int hi = (unsigned int)__builtin_amdgcn_readlane((int)(unsigned int)(v >> 32), l);
    return ((ull)hi << 32) | lo;
}
// LDS-only barrier: drain lgkm but leave global loads in flight.
__device__ __forceinline__ void barrier_lds() {
    asm volatile("s_waitcnt lgkmcnt(0)" ::: "memory");
    __builtin_amdgcn_s_barrier();
    asm volatile("" ::: "memory");
}

// ---------- 16384-bin histogram of ordered bits [30:16], LDS + global merge
__global__ __launch_bounds__(1024) void k_hist16(const float* __restrict__ cls,
                                                 unsigned int* __restrict__ hist) {
    __shared__ unsigned int h[NBIN];
    int img = blockIdx.y, part = blockIdx.x;
    int t = threadIdx.x;
    for (int b = t; b < NBIN; b += 1024) h[b] = 0;
    __syncthreads();
    int base = img * PER_IMG + part * (PER_IMG / HPART);
    for (int e = t; e < PER_IMG / HPART; e += 1024) {
        unsigned int u = f2ord(cls[base + e]);
        unsigned int bin = (u >> 16) - 0x8000u;
        if (bin > (NBIN - 1)) bin = NBIN - 1;  // safety clamp (impossible for [0,1))
        atomicAdd(&h[bin], 1u);
    }
    __syncthreads();
    unsigned int* hp = hist + (size_t)img * NBIN;
    for (int b = t; b < NBIN; b += 1024)
        if (h[b]) atomicAdd(&hp[b], h[b]);
}

// ---------- parallel suffix-scan: find max bin T with suffix >= PRE_N ----
__global__ __launch_bounds__(1024) void k_scan16(const unsigned int* __restrict__ hist,
                                                 unsigned int* __restrict__ meta) {
    __shared__ unsigned int csum[1024];
    __shared__ unsigned int aux[64];
    __shared__ unsigned int binv[16];
    int img = blockIdx.x, t = threadIdx.x;
    const unsigned int* hp = hist + (size_t)img * NBIN;
    unsigned int s = 0;
    #pragma unroll
    for (int q = 0; q < 16; ++q) s += hp[t * 16 + q];
    csum[t] = s;
    __syncthreads();
    if (t < 64) {
        unsigned int x = 0;
        #pragma unroll
        for (int q = 0; q < 16; ++q) x += csum[t * 16 + q];
        aux[t] = x;
    }
    __syncthreads();
    if (t < 64) {
        unsigned int suf = 0;
        for (int q = t; q < 64; ++q) suf += aux[q];
        ull mb1 = __ballot(suf >= PRE_N);
        int sstar = 63 - __clzll(mb1);
        unsigned int sufnext = (unsigned)__shfl((int)suf, (sstar + 1) & 63);
        unsigned int cumAbove = (sstar == 63) ? 0u : sufnext;
        unsigned int sufC = 0;
        if (t < 16) {
            for (int q = sstar * 16 + t; q < sstar * 16 + 16; ++q) sufC += csum[q];
            sufC += cumAbove;
        }
        ull mb2 = __ballot((t < 16) && (sufC >= PRE_N));
        int crel = 63 - __clzll(mb2);
        int cstar = sstar * 16 + crel;
        unsigned int cumAbove2 = (crel == 15) ? cumAbove : (unsigned)__shfl((int)sufC, crel + 1);
        if (t < 16) binv[t] = hp[cstar * 16 + t];
        unsigned int sufB = 0;
        if (t < 16) {
            for (int q = t; q < 16; ++q) sufB += binv[q];
            sufB += cumAbove2;
        }
        ull mb3 = __ballot((t < 16) && (sufB >= PRE_N));
        int brel = 63 - __clzll(mb3);
        if (t == 0) {
            meta[2 + img] = (unsigned)(cstar * 16 + brel) + 0x8000u;
            meta[img] = 0u;  // reset select counters for gather (every replay)
        }
    }
}

// ---------- gather candidates with (ord>>16) >= T, block-aggregated ------
__global__ __launch_bounds__(1024) void k_gather(const float* __restrict__ cls,
                                                 unsigned int* __restrict__ meta,
                                                 ull* __restrict__ selkeys) {
    __shared__ unsigned int lcnt[NIMG], lbase[NIMG];
    int t = threadIdx.x;
    int tid = blockIdx.x * 1024 + t;
    if (t < NIMG) lcnt[t] = 0;
    __syncthreads();
    unsigned int T0 = meta[2], T1 = meta[3];
    int a = tid / HW;
    int pos = tid - a * HW;          // h*WDIM + w
    int m = pos * A_NUM + a;         // (h,w,a) flattened order
    int lane = t & 63;
    unsigned int uv[NIMG];
    bool pr[NIMG];
    unsigned int lofs[NIMG];
    #pragma unroll
    for (int img = 0; img < NIMG; ++img) {
        unsigned int T = img ? T1 : T0;
        unsigned int u = f2ord(cls[img * PER_IMG + tid]);
        uv[img] = u;
        bool pred = (u >> 16) >= T;
        pr[img] = pred;
        ull mball = __ballot((int)pred);
        unsigned int o = 0;
        if (pred) {
            int leader = __ffsll((long long)mball) - 1;
            unsigned int wbase = 0;
            if (lane == leader) wbase = atomicAdd(&lcnt[img], (unsigned)__popcll(mball));
            wbase = (unsigned)__shfl((int)wbase, leader);
            o = wbase + (unsigned)__popcll(mball & ((1ull << lane) - 1ull));
        }
        lofs[img] = o;
    }
    __syncthreads();
    if (t < NIMG) lbase[t] = atomicAdd(&meta[t], lcnt[t]);
    __syncthreads();
    #pragma unroll
    for (int img = 0; img < NIMG; ++img) {
        if (pr[img]) {
            unsigned int p = lbase[img] + lofs[img];
            if (p < SORTN)
                selkeys[(size_t)img * SORTN + p] =
                    ((ull)(~uv[img]) << 32) | (unsigned int)m;
        }
    }
}

// ---------- bitonic: local sort of 4096-chunks (asc/desc), 1024 thr ------
__global__ __launch_bounds__(1024) void k_sortA(ull* __restrict__ selkeys,
                                                const unsigned int* __restrict__ meta) {
    __shared__ ull key[CHUNK4];   // 32 KB
    int img = blockIdx.x >> 1, c = blockIdx.x & 1;
    unsigned int cnt = meta[img];
    if (cnt > SORTN) cnt = SORTN;
    ull* g = selkeys + (size_t)img * SORTN;
    int base = c * CHUNK4;
    for (int i = threadIdx.x; i < CHUNK4; i += 1024)
        key[i] = (base + i < (int)cnt) ? g[base + i] : ~0ull;
    __syncthreads();
    bool desc = (c & 1);
    for (int k = 2; k <= CHUNK4; k <<= 1) {
        for (int j = k >> 1; j > 0; j >>= 1) {
            for (int p = threadIdx.x; p < CHUNK4 / 2; p += 1024) {
                int i = ((p & ~(j - 1)) << 1) | (p & (j - 1));
                int x = i | j;
                bool up = (((i & k) == 0) != desc);
                ull A = key[i], B = key[x];
                if ((A > B) == up) { key[i] = B; key[x] = A; }
            }
            __syncthreads();
        }
    }
    for (int i = threadIdx.x; i < CHUNK4; i += 1024) g[base + i] = key[i];
}

// ---------- bitonic: final k=8192 merge in one 64KB-LDS block, 1024 thr --
__global__ __launch_bounds__(1024) void k_sortC(ull* __restrict__ selkeys) {
    __shared__ ull key[SORTN];    // 64 KB
    int img = blockIdx.x;
    ull* g = selkeys + (size_t)img * SORTN;
    for (int i = threadIdx.x; i < SORTN; i += 1024) key[i] = g[i];
    __syncthreads();
    for (int j = SORTN / 2; j > 0; j >>= 1) {
        for (int p = threadIdx.x; p < SORTN / 2; p += 1024) {
            int i = ((p & ~(j - 1)) << 1) | (p & (j - 1));
            int x = i | j;
            ull A = key[i], B = key[x];   // k=8192 -> ascending everywhere
            if (A > B) { key[i] = B; key[x] = A; }
        }
        __syncthreads();
    }
    for (int i = threadIdx.x; i < PRE_N; i += 1024) g[i] = key[i];
}

// ---------- decode boxes; emit per-block valid ballots -------------------
__global__ void k_decode(const ull* __restrict__ selkeys,
                         const float* __restrict__ bbox, const float* __restrict__ anchors,
                         const float* __restrict__ iminfo,
                         float* __restrict__ boxsoa, ull* __restrict__ validwArr) {
    int r = blockIdx.x * blockDim.x + threadIdx.x;
    int img = blockIdx.y;
    bool in = r < PRE_N;
    int rr = in ? r : 0;                 // clamp: pad keys may hold garbage m
    ull keyv = selkeys[(size_t)img * SORTN + rr];
    unsigned int m = (unsigned int)(keyv & 0xFFFFFFFFu);
    unsigned int u = ~(unsigned int)(keyv >> 32);
    float score = ord2f(u);
    int q = m / A_NUM;
    int a = m - q * A_NUM;
    int w = q & (WDIM - 1);
    int h = q >> 7;
    // reference's meshgrid quirk -> x-shift from h, y-shift from w
    float sx = (float)h * 8.0f;
    float sy = (float)w * 8.0f;
    float a0 = __fadd_rn(anchors[a * 4 + 0], sx);
    float a1 = __fadd_rn(anchors[a * 4 + 1], sy);
    float a2 = __fadd_rn(anchors[a * 4 + 2], sx);
    float a3 = __fadd_rn(anchors[a * 4 + 3], sy);
    float ws = __fadd_rn(__fsub_rn(a2, a0), 1.0f);
    float hs = __fadd_rn(__fsub_rn(a3, a1), 1.0f);
    float cx = __fadd_rn(a0, __fmul_rn(0.5f, ws));
    float cy = __fadd_rn(a1, __fmul_rn(0.5f, hs));
    const float* bb = bbox + (size_t)img * 4 * A_NUM * HW;
    int base = h * WDIM + w;
    float dx = bb[(a * 4 + 0) * HW + base];
    float dy = bb[(a * 4 + 1) * HW + base];
    float dwv = bb[(a * 4 + 2) * HW + base];
    float dhv = bb[(a * 4 + 3) * HW + base];
    const float CLIPV = 4.135166556742356f;  // np.float32(log(1000/16))
    float dw = fminf(dwv, CLIPV);
    float dh = fminf(dhv, CLIPV);
    float pcx = __fadd_rn(__fmul_rn(dx, ws), cx);
    float pcy = __fadd_rn(__fmul_rn(dy, hs), cy);
    float pw = __fmul_rn(expf(dw), ws);
    float ph = __fmul_rn(expf(dh), hs);
    float x1 = __fsub_rn(pcx, __fmul_rn(0.5f, pw));
    float y1 = __fsub_rn(pcy, __fmul_rn(0.5f, ph));
    float x2 = __fsub_rn(__fadd_rn(pcx, __fmul_rn(0.5f, pw)), 1.0f);
    float y2 = __fsub_rn(__fadd_rn(pcy, __fmul_rn(0.5f, ph)), 1.0f);
    float him = iminfo[img * 3 + 0], wim = iminfo[img * 3 + 1], scale = iminfo[img * 3 + 2];
    float wmax = __fsub_rn(wim, 1.0f), hmax = __fsub_rn(him, 1.0f);
    x1 = fminf(fmaxf(x1, 0.0f), wmax);
    y1 = fminf(fmaxf(y1, 0.0f), hmax);
    x2 = fminf(fmaxf(x2, 0.0f), wmax);
    y2 = fminf(fmaxf(y2, 0.0f), hmax);
    float bws = __fadd_rn(__fsub_rn(x2, x1), 1.0f);
    float bhs = __fadd_rn(__fsub_rn(y2, y1), 1.0f);
    float minsz = __fmul_rn(0.0f, scale);  // MIN_SIZE * scale
    bool valid = (bws >= minsz) && (bhs >= minsz) &&
                 (__fadd_rn(x1, __fdiv_rn(bws, 2.0f)) < wim) &&
                 (__fadd_rn(y1, __fdiv_rn(bhs, 2.0f)) < him);
    float area = __fmul_rn(bws, bhs);
    if (in) {
        boxsoa[(0 * NIMG + img) * NPAD + r] = x1;
        boxsoa[(1 * NIMG + img) * NPAD + r] = y1;
        boxsoa[(2 * NIMG + img) * NPAD + r] = x2;
        boxsoa[(3 * NIMG + img) * NPAD + r] = y2;
        boxsoa[(4 * NIMG + img) * NPAD + r] = area;
        boxsoa[(5 * NIMG + img) * NPAD + r] = score;
    }
    ull bw = __ballot((int)(in && valid));
    if ((threadIdx.x & 63) == 0) {
        int blk = r >> 6;
        if (blk < NBLK) validwArr[img * 128 + blk] = bw;
    }
}

// ---------- COLUMN-major suppression matrix Mc[img][cb][r] ---------------
// Mc[cb][r] bit jj = iou(box r, box cb*64+jj) > 0.7, (cb*64+jj) != r.
// Only row-blocks rb <= cb computed (reduce reads rows r <= cb*64+63).
__global__ __launch_bounds__(256) void k_mask(const float* __restrict__ boxsoa,
                                              ull* __restrict__ Mc) {
    int cb = blockIdx.x, rbq = blockIdx.y, img = blockIdx.z;
    if ((rbq << 2) > cb) return;          // whole quad below row<=col boundary
    int t = threadIdx.x, wv = t >> 6, lane = t & 63;
    __shared__ float jx1[64], jy1[64], jx2[64], jy2[64], jar[64];
    const float* X1 = boxsoa + (0 * NIMG + img) * NPAD;
    const float* Y1 = boxsoa + (1 * NIMG + img) * NPAD;
    const float* X2 = boxsoa + (2 * NIMG + img) * NPAD;
    const float* Y2 = boxsoa + (3 * NIMG + img) * NPAD;
    const float* AR = boxsoa + (4 * NIMG + img) * NPAD;
    int j0 = cb * 64;
    if (t < 64) {
        int jidx = j0 + t;
        bool jin = jidx < PRE_N;
        jx1[t] = jin ? X1[jidx] : 0.0f;
        jy1[t] = jin ? Y1[jidx] : 0.0f;
        jx2[t] = jin ? X2[jidx] : 0.0f;
        jy2[t] = jin ? Y2[jidx] : 0.0f;
        jar[t] = jin ? AR[jidx] : 1.0f;
    }
    __syncthreads();
    int rb = rbq * 4 + wv;
    if (rb > cb) return;
    int r = rb * 64 + lane;
    ull bits = 0ULL;
    if (r < PRE_N) {
        float x1 = X1[r], y1 = Y1[r], x2 = X2[r], y2 = Y2[r], ai = AR[r];
        for (int jj = 0; jj < 64; ++jj) {
            int j = j0 + jj;
            if (j == r || j >= PRE_N) continue;
            float ix1 = fmaxf(x1, jx1[jj]);
            float iy1 = fmaxf(y1, jy1[jj]);
            float ix2 = fminf(x2, jx2[jj]);
            float iy2 = fminf(y2, jy2[jj]);
            float iw = fmaxf(__fadd_rn(__fsub_rn(ix2, ix1), 1.0f), 0.0f);
            float ih = fmaxf(__fadd_rn(__fsub_rn(iy2, iy1), 1.0f), 0.0f);
            float inter = __fmul_rn(iw, ih);
            float denom = __fsub_rn(__fadd_rn(ai, jar[jj]), inter);
            float iou = __fdiv_rn(inter, denom);
            if (iou > 0.7f) bits |= (1ULL << jj);
        }
    }
    Mc[((size_t)img * NBLK + cb) * NPAD + r] = bits;
}

// ---------- greedy reduce: retimed fold || chain, ONE barrier/step -------
// (R20/R22-verified structure, best known: ~127 us.)  Step ib:
//   wave0:   sup = OR(partial[ib&1][1..7]) | fix(block ib-1 @ col ib,
//            masked by keptLDS[ib-1]) -> butterfly -> readlane chain.
//   waves1-7: ds_write col ib+2 (2-step parity regs); load col ib+4;
//            fold col ib+1 over blocks 0..ib-1 into partial[(ib+1)&1].
__global__ __launch_bounds__(512, 1) void k_reduce(const ull* __restrict__ Mc,
                                                   const ull* __restrict__ validwArr,
                                                   const float* __restrict__ boxsoa,
                                                   float* __restrict__ out) {
    __shared__ ull buf[3][NPAD];          // 144384 B ring of 3 columns
    __shared__ ull keptLDS[NBLK];
    __shared__ ull partial[2][8][64];     // [parity][wave][lane]
    __shared__ unsigned short s_list[POST_N];
    __shared__ int s_stop, s_cnt;
    int img = blockIdx.x;
    int tid = threadIdx.x;
    int wv = tid >> 6, lane = tid & 63;
    const ull* MCI = Mc + (size_t)img * NBLK * NPAD;
    ull vw_a = 0, vw_b = 0;
    ull rbufA[WPT], rbufB[WPT];           // parity 0 / parity 1 reg buffers
    #pragma unroll
    for (int q = 0; q < WPT; ++q) { rbufA[q] = 0ULL; rbufB[q] = 0ULL; }
    int pid = tid - 64;
    if (wv == 0) {
        vw_a = validwArr[img * 128 + lane];
        vw_b = (lane + 64 < NBLK) ? validwArr[img * 128 + lane + 64] : 0ULL;
        if (lane == 0) { s_stop = 0; s_cnt = 0; }
        partial[0][0][lane] = 0ULL;       // wave0 never writes partials later
        partial[1][0][lane] = 0ULL;
    } else {
        // prologue: col0 -> buf[0]; col1 -> buf[1]; col2 -> rbufA; col3 -> rbufB
        #pragma unroll
        for (int q = 0; q < WPT; ++q) {
            int w = pid + PROD_T * q;
            rbufA[q] = (w < 64) ? MCI[w] : 0ULL;
        }
        #pragma unroll
        for (int q = 0; q < WPT; ++q) {
            int w = pid + PROD_T * q;
            if (w < 64) buf[0][w] = rbufA[q];
        }
        #pragma unroll
        for (int q = 0; q < WPT; ++q) {
            int w = pid + PROD_T * q;
            rbufB[q] = (w < 128) ? MCI[NPAD + w] : 0ULL;
        }
        #pragma unroll
        for (int q = 0; q < WPT; ++q) {
            int w = pid + PROD_T * q;
            if (w < 128) buf[1][w] = rbufB[q];
        }
        #pragma unroll
        for (int q = 0; q < WPT; ++q) {
            int w = pid + PROD_T * q;
            rbufA[q] = (w < 192) ? MCI[2 * (size_t)NPAD + w] : 0ULL;
        }
        #pragma unroll
        for (int q = 0; q < WPT; ++q) {
            int w = pid + PROD_T * q;
            rbufB[q] = (w < 256) ? MCI[3 * (size_t)NPAD + w] : 0ULL;
        }
        // zero partials for both parities (wave q covers its own slot)
        partial[0][wv][lane] = 0ULL;
        partial[1][wv][lane] = 0ULL;
    }
    __syncthreads();
    int cnt = 0;
    for (int ib = 0; ib < NBLK; ++ib) {
        int bcur = ib % 3, bn1 = (ib + 1) % 3, bn2 = (ib + 2) % 3;
        if (wv == 0) {
            // ---- sup = partials(col ib: blocks 0..ib-2) | fix(block ib-1)
            ull acc = 0ULL;
            if (ib > 0) {
                #pragma unroll
                for (int q = 1; q < 8; ++q) acc |= partial[ib & 1][q][lane];
                ull kwp = keptLDS[ib - 1];
                acc |= (0ULL - ((kwp >> lane) & 1ULL)) & buf[bcur][(ib - 1) * 64 + lane];
            }
            unsigned int lo = (unsigned)acc, hi = (unsigned)(acc >> 32);
            #pragma unroll
            for (int s2 = 1; s2 < 64; s2 <<= 1) {
                lo |= (unsigned)__shfl_xor((int)lo, s2);
                hi |= (unsigned)__shfl_xor((int)hi, s2);
            }
            ull sup = ((ull)hi << 32) | lo;
            ull validw = (ib < 64) ? readlane64(vw_a, ib) : readlane64(vw_b, ib - 64);
            ull d = buf[bcur][ib * 64 + lane];
            ull live = validw & ~sup;
            unsigned int dlo = (unsigned)d, dhi = (unsigned)(d >> 32);
            ull keptb = 0ULL;
            while (live) {
                int b = __ffsll((long long)live) - 1;
                keptb |= 1ULL << b;
                if (lane == 0) s_list[cnt] = (unsigned short)(ib * 64 + b);
                ++cnt;
                if (cnt >= POST_N) break;
                unsigned int rl = (unsigned)__builtin_amdgcn_readlane((int)dlo, b);
                unsigned int rh = (unsigned)__builtin_amdgcn_readlane((int)dhi, b);
                live &= ~(((ull)rh << 32) | rl);
                live &= ~(1ULL << b);
            }
            if (lane == 0) {
                keptLDS[ib] = keptb;
                s_cnt = cnt;
                if (cnt >= POST_N) s_stop = 1;
            }
        } else {
            // ---- stage: ds_write col ib+2 (loaded 2 steps ago); load col ib+4
            int c_w = ib + 2;
            if (c_w < NBLK) {
                int Ww = (c_w + 1) * 64;
                if (Ww > NPAD) Ww = NPAD;
                if (ib & 1) {
                    #pragma unroll
                    for (int q = 0; q < WPT; ++q) {
                        int w = pid + PROD_T * q;
                        if (w < Ww) buf[bn2][w] = rbufB[q];
                    }
                } else {
                    #pragma unroll
                    for (int q = 0; q < WPT; ++q) {
                        int w = pid + PROD_T * q;
                        if (w < Ww) buf[bn2][w] = rbufA[q];
                    }
                }
            }
            int c_l = ib + 4;
            if (c_l < NBLK) {
                int Wn = (c_l + 1) * 64;
                if (Wn > NPAD) Wn = NPAD;
                const ull* gn = MCI + (size_t)c_l * NPAD;
                if (ib & 1) {
                    #pragma unroll
                    for (int q = 0; q < WPT; ++q) {
                        int w = pid + PROD_T * q;
                        rbufB[q] = (w < Wn) ? gn[w] : 0ULL;
                    }
                } else {
                    #pragma unroll
                    for (int q = 0; q < WPT; ++q) {
                        int w = pid + PROD_T * q;
                        rbufA[q] = (w < Wn) ? gn[w] : 0ULL;
                    }
                }
            }
            // ---- fold col ib+1 over blocks 0..ib-1 (no dep on this chain)
            if (ib + 1 < NBLK) {
                ull part = 0ULL;
                for (int u = wv - 1; u <= ib - 1; u += 7) {
                    ull kw = keptLDS[u];
                    ull v = buf[bn1][u * 64 + lane];
                    part |= (0ULL - ((kw >> lane) & 1ULL)) & v;
                }
                partial[(ib + 1) & 1][wv][lane] = part;
            }
        }
        barrier_lds();                    // ONE barrier per step
        if (s_stop) break;
    }
    // drain outstanding producer loads before exit (determinism across replays)
    asm volatile("s_waitcnt vmcnt(0) lgkmcnt(0)" ::: "memory");
    __syncthreads();
    int total = s_cnt > POST_N ? POST_N : s_cnt;
    for (int k = tid; k < POST_N; k += 512) {
        float x1 = 0.0f, y1 = 0.0f, x2 = 0.0f, y2 = 0.0f, sc = -1.0f;
        if (k < total) {
            int r = (int)s_list[k];
            x1 = boxsoa[(0 * NIMG + img) * NPAD + r];
            y1 = boxsoa[(1 * NIMG + img) * NPAD + r];
            x2 = boxsoa[(2 * NIMG + img) * NPAD + r];
            y2 = boxsoa[(3 * NIMG + img) * NPAD + r];
            sc = boxsoa[(5 * NIMG + img) * NPAD + r];
        }
        float* roi = out + (size_t)(img * POST_N + k) * 5;
        roi[0] = (float)img;
        roi[1] = x1;
        roi[2] = y1;
        roi[3] = x2;
        roi[4] = y2;
        out[NIMG * POST_N * 5 + img * POST_N + k] = sc;
    }
}

extern "C" void kernel_launch(void* const* d_in, const int* in_sizes, int n_in,
                              void* d_out, int out_size, void* d_ws, size_t ws_size,
                              hipStream_t stream) {
    const float* cls = (const float*)d_in[0];
    const float* bbox = (const float*)d_in[1];
    const float* iminfo = (const float*)d_in[2];
    const float* anchors = (const float*)d_in[3];
    float* out = (float*)d_out;
    char* ws = (char*)d_ws;

    unsigned int* meta = (unsigned int*)(ws + META_OFF);
    unsigned int* hist = (unsigned int*)(ws + HIST_OFF);
    ull* selkeys = (ull*)(ws + SEL_OFF);
    float* boxsoa = (float*)(ws + BOX_OFF);
    ull* validwArr = (ull*)(ws + VALIDW_OFF);
    ull* mask = (ull*)(ws + MASK_OFF);

    hipMemsetAsync(hist, 0, (size_t)NIMG * NBIN * sizeof(unsigned int), stream);
    k_hist16<<<dim3(HPART, NIMG), 1024, 0, stream>>>(cls, hist);
    k_scan16<<<NIMG, 1024, 0, stream>>>(hist, meta);
    k_gather<<<PER_IMG / 1024, 1024, 0, stream>>>(cls, meta, selkeys);
    k_sortA<<<2 * NIMG, 1024, 0, stream>>>(selkeys, meta);
    k_sortC<<<NIMG, 1024, 0, stream>>>(selkeys);
    k_decode<<<dim3((PRE_N + 255) / 256, NIMG), 256, 0, stream>>>(selkeys, bbox, anchors, iminfo,
                                                                  boxsoa, validwArr);
    k_mask<<<dim3(NBLK, (NBLK + 3) / 4, NIMG), 256, 0, stream>>>(boxsoa, mask);
    k_reduce<<<NIMG, 512, 0, stream>>>(mask, validwArr, boxsoa, out);
}